// Round 2
// baseline (99.711 us; speedup 1.0000x reference)
//
#include <hip/hip_runtime.h>
#include <math.h>

// Problem constants (match reference)
#define BATCH   32768
#define DMODEL  1024
#define NTIERS  3

// One 256-thread block per batch row.
// Thread t owns float4 elements [4t, 4t+3] of the 1024-wide row.
__global__ __launch_bounds__(256) void sparse_router_kernel(
    const float* __restrict__ tier_outputs,  // (B, 3, D)
    const float* __restrict__ query,         // (B, D)
    const float* __restrict__ W,             // (3, D)
    float* __restrict__ merged,              // (B, D)
    float* __restrict__ gate,                // (B, 3)
    float* __restrict__ logits_out)          // (B, 3)
{
    const int b   = blockIdx.x;
    const int tid = threadIdx.x;

    // ---- Phase 1: partial dot products q . W[t] for t = 0,1,2 ----
    const float4* q4 = reinterpret_cast<const float4*>(query + (size_t)b * DMODEL);
    const float4  q  = q4[tid];

    const float4* w4 = reinterpret_cast<const float4*>(W);
    const float4  w0 = w4[tid];                  // W[0]
    const float4  w1 = w4[tid + DMODEL / 4];     // W[1]
    const float4  w2 = w4[tid + 2 * DMODEL / 4]; // W[2]

    float p0 = q.x * w0.x + q.y * w0.y + q.z * w0.z + q.w * w0.w;
    float p1 = q.x * w1.x + q.y * w1.y + q.z * w1.z + q.w * w1.w;
    float p2 = q.x * w2.x + q.y * w2.y + q.z * w2.z + q.w * w2.w;

    // Wave (64-lane) butterfly reduce
    #pragma unroll
    for (int off = 32; off >= 1; off >>= 1) {
        p0 += __shfl_down(p0, off);
        p1 += __shfl_down(p1, off);
        p2 += __shfl_down(p2, off);
    }

    __shared__ float red0[4], red1[4], red2[4];
    __shared__ float s_w[2];
    __shared__ int   s_i[2];

    const int wave = tid >> 6;
    const int lane = tid & 63;
    if (lane == 0) { red0[wave] = p0; red1[wave] = p1; red2[wave] = p2; }
    __syncthreads();

    // ---- Phase 2: top-2 of 3, softmax, write small outputs ----
    if (tid == 0) {
        float l[NTIERS];
        l[0] = red0[0] + red0[1] + red0[2] + red0[3];
        l[1] = red1[0] + red1[1] + red1[2] + red1[3];
        l[2] = red2[0] + red2[1] + red2[2] + red2[3];

        // argmax with strict > : lowest index wins ties (matches lax.top_k)
        int i0 = 0;
        if (l[1] > l[i0]) i0 = 1;
        if (l[2] > l[i0]) i0 = 2;
        int i1 = -1;
        #pragma unroll
        for (int t = 0; t < NTIERS; ++t) {
            if (t == i0) continue;
            if (i1 < 0 || l[t] > l[i1]) i1 = t;
        }

        const float v0 = l[i0];
        const float v1 = l[i1];
        const float e1 = expf(v1 - v0);       // v0 >= v1, numerically safe
        const float inv = 1.0f / (1.0f + e1);
        const float g0 = inv;
        const float g1 = e1 * inv;

        float gd[NTIERS] = {0.0f, 0.0f, 0.0f};
        gd[i0] = g0;
        gd[i1] = g1;

        const size_t o3 = (size_t)b * NTIERS;
        logits_out[o3 + 0] = l[0];
        logits_out[o3 + 1] = l[1];
        logits_out[o3 + 2] = l[2];
        gate[o3 + 0] = gd[0];
        gate[o3 + 1] = gd[1];
        gate[o3 + 2] = gd[2];

        s_w[0] = g0; s_w[1] = g1;
        s_i[0] = i0; s_i[1] = i1;
    }
    __syncthreads();

    // ---- Phase 3: merged = g0 * tier[i0] + g1 * tier[i1] ----
    const float gA = s_w[0];
    const float gB = s_w[1];
    const size_t baseA = ((size_t)b * NTIERS + s_i[0]) * DMODEL;
    const size_t baseB = ((size_t)b * NTIERS + s_i[1]) * DMODEL;

    const float4 a = reinterpret_cast<const float4*>(tier_outputs + baseA)[tid];
    const float4 c = reinterpret_cast<const float4*>(tier_outputs + baseB)[tid];

    float4 m;
    m.x = gA * a.x + gB * c.x;
    m.y = gA * a.y + gB * c.y;
    m.z = gA * a.z + gB * c.z;
    m.w = gA * a.w + gB * c.w;

    reinterpret_cast<float4*>(merged + (size_t)b * DMODEL)[tid] = m;
}

extern "C" void kernel_launch(void* const* d_in, const int* in_sizes, int n_in,
                              void* d_out, int out_size, void* d_ws, size_t ws_size,
                              hipStream_t stream) {
    const float* tier_outputs = (const float*)d_in[0];  // (B, 3, D)
    const float* query        = (const float*)d_in[1];  // (B, D)
    const float* W            = (const float*)d_in[2];  // (3, D)

    float* out = (float*)d_out;
    float* merged     = out;                                   // B*D
    float* gate       = out + (size_t)BATCH * DMODEL;          // B*3
    float* logits_out = gate + (size_t)BATCH * NTIERS;         // B*3

    sparse_router_kernel<<<BATCH, 256, 0, stream>>>(
        tier_outputs, query, W, merged, gate, logits_out);
}

// Round 5
// 88.310 us; speedup vs baseline: 1.1291x; 1.1291x over previous
//
#include <hip/hip_runtime.h>
#include <math.h>

// Problem constants (match reference)
#define BATCH   32768
#define DMODEL  1024
#define NTIERS  3
#define F4_PER_ROW (DMODEL / 4)   // 256 float4 per 1024-wide row
#define F4_PER_LANE 4             // 256 / 64 lanes

// Native clang vector type — required by __builtin_nontemporal_load/store
// (HIP's float4 is a class and is rejected by the builtin).
typedef float f32x4 __attribute__((ext_vector_type(4)));

// One 64-lane wave per batch row; 4 rows per 256-thread block.
// No __syncthreads, no LDS. Lane owns interleaved float4s j*64+lane
// (fully coalesced 1KB per load instruction).
__global__ __launch_bounds__(256) void sparse_router_kernel(
    const float* __restrict__ tier_outputs,  // (B, 3, D)
    const float* __restrict__ query,         // (B, D)
    const float* __restrict__ W,             // (3, D)
    float* __restrict__ merged,              // (B, D)
    float* __restrict__ gate,                // (B, 3)
    float* __restrict__ logits_out)          // (B, 3)
{
    const int wave = threadIdx.x >> 6;
    const int lane = threadIdx.x & 63;
    const int b    = blockIdx.x * 4 + wave;   // one row per wave

    // ---- Phase 1: q . W[t], t=0..2 ----
    const f32x4* q4 = reinterpret_cast<const f32x4*>(query + (size_t)b * DMODEL);
    f32x4 q[F4_PER_LANE];
    #pragma unroll
    for (int j = 0; j < F4_PER_LANE; ++j)
        q[j] = __builtin_nontemporal_load(&q4[j * 64 + lane]);   // streamed, no reuse

    const f32x4* w4 = reinterpret_cast<const f32x4*>(W);         // 12KB, cached
    float p0 = 0.f, p1 = 0.f, p2 = 0.f;
    #pragma unroll
    for (int j = 0; j < F4_PER_LANE; ++j) {
        const f32x4 w0 = w4[0 * F4_PER_ROW + j * 64 + lane];
        const f32x4 w1 = w4[1 * F4_PER_ROW + j * 64 + lane];
        const f32x4 w2 = w4[2 * F4_PER_ROW + j * 64 + lane];
        p0 += q[j].x * w0.x + q[j].y * w0.y + q[j].z * w0.z + q[j].w * w0.w;
        p1 += q[j].x * w1.x + q[j].y * w1.y + q[j].z * w1.z + q[j].w * w1.w;
        p2 += q[j].x * w2.x + q[j].y * w2.y + q[j].z * w2.z + q[j].w * w2.w;
    }

    // Full-wave butterfly: sums end up in ALL lanes (no broadcast needed)
    #pragma unroll
    for (int off = 1; off <= 32; off <<= 1) {
        p0 += __shfl_xor(p0, off);
        p1 += __shfl_xor(p1, off);
        p2 += __shfl_xor(p2, off);
    }

    // ---- Phase 2: top-2 of 3 + softmax, redundantly in every lane ----
    float l[NTIERS] = {p0, p1, p2};
    int i0 = 0;                               // strict > : low index wins ties
    if (l[1] > l[i0]) i0 = 1;
    if (l[2] > l[i0]) i0 = 2;
    int i1 = -1;
    #pragma unroll
    for (int t = 0; t < NTIERS; ++t) {
        if (t == i0) continue;
        if (i1 < 0 || l[t] > l[i1]) i1 = t;
    }

    const float e1  = expf(l[i1] - l[i0]);    // l[i0] >= l[i1], safe
    const float inv = 1.0f / (1.0f + e1);
    const float g0  = inv;
    const float g1  = e1 * inv;

    if (lane < NTIERS) {
        const size_t o3 = (size_t)b * NTIERS + lane;
        logits_out[o3] = l[lane];
        gate[o3]       = (lane == i0) ? g0 : (lane == i1) ? g1 : 0.0f;
    }

    // ---- Phase 3: merged = g0 * tier[i0] + g1 * tier[i1] ----
    const f32x4* tA = reinterpret_cast<const f32x4*>(
        tier_outputs + ((size_t)b * NTIERS + i0) * DMODEL);
    const f32x4* tB = reinterpret_cast<const f32x4*>(
        tier_outputs + ((size_t)b * NTIERS + i1) * DMODEL);
    f32x4* mo = reinterpret_cast<f32x4*>(merged + (size_t)b * DMODEL);

    f32x4 a[F4_PER_LANE], c[F4_PER_LANE];
    #pragma unroll
    for (int j = 0; j < F4_PER_LANE; ++j) {
        a[j] = __builtin_nontemporal_load(&tA[j * 64 + lane]);
        c[j] = __builtin_nontemporal_load(&tB[j * 64 + lane]);
    }
    #pragma unroll
    for (int j = 0; j < F4_PER_LANE; ++j) {
        f32x4 m;
        m.x = g0 * a[j].x + g1 * c[j].x;
        m.y = g0 * a[j].y + g1 * c[j].y;
        m.z = g0 * a[j].z + g1 * c[j].z;
        m.w = g0 * a[j].w + g1 * c[j].w;
        __builtin_nontemporal_store(m, &mo[j * 64 + lane]);
    }
}

extern "C" void kernel_launch(void* const* d_in, const int* in_sizes, int n_in,
                              void* d_out, int out_size, void* d_ws, size_t ws_size,
                              hipStream_t stream) {
    const float* tier_outputs = (const float*)d_in[0];  // (B, 3, D)
    const float* query        = (const float*)d_in[1];  // (B, D)
    const float* W            = (const float*)d_in[2];  // (3, D)

    float* out = (float*)d_out;
    float* merged     = out;                            // B*D
    float* gate       = out + (size_t)BATCH * DMODEL;   // B*3
    float* logits_out = gate + (size_t)BATCH * NTIERS;  // B*3

    sparse_router_kernel<<<BATCH / 4, 256, 0, stream>>>(
        tier_outputs, query, W, merged, gate, logits_out);
}